// Round 1
// baseline (1223.007 us; speedup 1.0000x reference)
//
#include <hip/hip_runtime.h>
#include <math.h>

#define NN 100000
#define NE 1600000
#define DIM 128
#define SCHUNK 1024

// ---------------- degree / norm ----------------
__global__ void k_deg(const int* __restrict__ dst, int* __restrict__ deg) {
  int i = blockIdx.x * blockDim.x + threadIdx.x;
  if (i < NE) atomicAdd(&deg[dst[i]], 1);
}

__global__ void k_dinv(const int* __restrict__ deg, float* __restrict__ dinv) {
  int i = blockIdx.x * blockDim.x + threadIdx.x;
  if (i < NN) dinv[i] = rsqrtf((float)deg[i] + 1.0f);
}

// ---------------- exclusive prefix scan of deg -> offs ----------------
__global__ void k_scan1(const int* __restrict__ deg, int* __restrict__ bsum) {
  __shared__ int sd[256];
  int t = threadIdx.x;
  int base = blockIdx.x * SCHUNK + t * 4;
  int s = 0;
#pragma unroll
  for (int j = 0; j < 4; ++j) { int idx = base + j; if (idx < NN) s += deg[idx]; }
  sd[t] = s; __syncthreads();
  for (int off = 128; off > 0; off >>= 1) {
    if (t < off) sd[t] += sd[t + off];
    __syncthreads();
  }
  if (t == 0) bsum[blockIdx.x] = sd[0];
}

__global__ void k_scan2(int* __restrict__ bsum, int nb) {
  if (threadIdx.x == 0 && blockIdx.x == 0) {
    int run = 0;
    for (int b = 0; b < nb; ++b) { int v = bsum[b]; bsum[b] = run; run += v; }
  }
}

__global__ void k_scan3(const int* __restrict__ deg, const int* __restrict__ bsum,
                        int* __restrict__ offs) {
  __shared__ int ts[256];
  int t = threadIdx.x;
  int base = blockIdx.x * SCHUNK + t * 4;
  int v[4]; int loc = 0;
#pragma unroll
  for (int j = 0; j < 4; ++j) { int idx = base + j; v[j] = (idx < NN) ? deg[idx] : 0; loc += v[j]; }
  ts[t] = loc; __syncthreads();
  for (int off = 1; off < 256; off <<= 1) {
    int x = (t >= off) ? ts[t - off] : 0;
    __syncthreads();
    ts[t] += x;
    __syncthreads();
  }
  int run = bsum[blockIdx.x] + ts[t] - loc;
#pragma unroll
  for (int j = 0; j < 4; ++j) { int idx = base + j; if (idx < NN) offs[idx] = run; run += v[j]; }
}

__global__ void k_fill(const int* __restrict__ src, const int* __restrict__ dst,
                       const int* __restrict__ offs, int* __restrict__ cur,
                       int* __restrict__ csr_src) {
  int i = blockIdx.x * blockDim.x + threadIdx.x;
  if (i < NE) {
    int d = dst[i];
    int pos = offs[d] + atomicAdd(&cur[d], 1);
    csr_src[pos] = src[i];
  }
}

// ---------------- GEMM: C[NN,128] = X[NN,128] @ W[128,128] ----------------
__launch_bounds__(256)
__global__ void k_gemm(const float* __restrict__ X, const float* __restrict__ W,
                       float* __restrict__ C) {
  __shared__ float xs[32][36];     // 32 rows x 32 k (padded, 144B rows keep float4 aligned)
  __shared__ float ws[32][128];    // 32 k x 128 cols
  int t = threadIdx.x;
  int tx = t & 31, ty = t >> 5;    // tx: col group (4 cols), ty: row group (4 rows)
  int row0 = blockIdx.x * 32;
  int c0 = tx * 4;
  float acc[4][4];
#pragma unroll
  for (int i = 0; i < 4; ++i)
#pragma unroll
    for (int j = 0; j < 4; ++j) acc[i][j] = 0.f;

  for (int k0 = 0; k0 < DIM; k0 += 32) {
    int r = t >> 3, cc = (t & 7) * 4;
    *(float4*)&xs[r][cc] = *(const float4*)&X[(size_t)(row0 + r) * DIM + k0 + cc];
#pragma unroll
    for (int i = 0; i < 4; ++i) {
      int kr = ty + i * 8;
      *(float4*)&ws[kr][tx * 4] = *(const float4*)&W[(size_t)(k0 + kr) * DIM + tx * 4];
    }
    __syncthreads();
#pragma unroll
    for (int kk = 0; kk < 32; kk += 4) {
      float4 xv[4], wv[4];
#pragma unroll
      for (int i = 0; i < 4; ++i) xv[i] = *(const float4*)&xs[ty * 4 + i][kk];
#pragma unroll
      for (int j = 0; j < 4; ++j) wv[j] = *(const float4*)&ws[kk + j][c0];
#pragma unroll
      for (int i = 0; i < 4; ++i) {
        acc[i][0] += xv[i].x * wv[0].x + xv[i].y * wv[1].x + xv[i].z * wv[2].x + xv[i].w * wv[3].x;
        acc[i][1] += xv[i].x * wv[0].y + xv[i].y * wv[1].y + xv[i].z * wv[2].y + xv[i].w * wv[3].y;
        acc[i][2] += xv[i].x * wv[0].z + xv[i].y * wv[1].z + xv[i].z * wv[2].z + xv[i].w * wv[3].z;
        acc[i][3] += xv[i].x * wv[0].w + xv[i].y * wv[1].w + xv[i].z * wv[2].w + xv[i].w * wv[3].w;
      }
    }
    __syncthreads();
  }
#pragma unroll
  for (int i = 0; i < 4; ++i) {
    int row = row0 + ty * 4 + i;
    *(float4*)&C[(size_t)row * DIM + c0] = make_float4(acc[i][0], acc[i][1], acc[i][2], acc[i][3]);
  }
}

// ---------------- aggregation: out[n] = sum_in(norm*h[src]) + self + bias (opt relu) ----
__global__ void k_agg(const float* __restrict__ h, const int* __restrict__ csr_src,
                      const int* __restrict__ offs, const int* __restrict__ deg,
                      const float* __restrict__ dinv, const float* __restrict__ bias,
                      float* __restrict__ out, int relu) {
  int n = blockIdx.x;
  int c = threadIdx.x;                  // 128 threads = one channel each
  float dn = dinv[n];
  int s = offs[n], cnt = deg[n];
  float acc = 0.f;
  for (int i = 0; i < cnt; ++i) {
    int u = csr_src[s + i];
    acc += dinv[u] * h[(size_t)u * DIM + c];
  }
  acc = acc * dn + h[(size_t)n * DIM + c] * (dn * dn) + bias[c];
  out[(size_t)n * DIM + c] = relu ? fmaxf(acc, 0.f) : acc;
}

// ---------------- edge decode: sigmoid(dot(z[src], z[dst])) ----------------
__global__ void k_decode(const float* __restrict__ z, const int* __restrict__ src,
                         const int* __restrict__ dst, float* __restrict__ out) {
  int g = blockIdx.x * blockDim.x + threadIdx.x;
  int l = g & 15;
  int e = g >> 4;
  if (e >= NE) return;
  int s = src[e], d = dst[e];
  const float4* zs = (const float4*)(z + (size_t)s * DIM);
  const float4* zd = (const float4*)(z + (size_t)d * DIM);
  float4 a0 = zs[l * 2], a1 = zs[l * 2 + 1];
  float4 b0 = zd[l * 2], b1 = zd[l * 2 + 1];
  float p = a0.x * b0.x + a0.y * b0.y + a0.z * b0.z + a0.w * b0.w
          + a1.x * b1.x + a1.y * b1.y + a1.z * b1.z + a1.w * b1.w;
#pragma unroll
  for (int off = 8; off >= 1; off >>= 1) p += __shfl_xor(p, off);
  if (l == 0) out[e] = 1.0f / (1.0f + expf(-p));
}

extern "C" void kernel_launch(void* const* d_in, const int* in_sizes, int n_in,
                              void* d_out, int out_size, void* d_ws, size_t ws_size,
                              hipStream_t stream) {
  const float* x  = (const float*)d_in[0];
  const float* W1 = (const float*)d_in[1];
  const float* b1 = (const float*)d_in[2];
  const float* W2 = (const float*)d_in[3];
  const float* b2 = (const float*)d_in[4];
  const float* W3 = (const float*)d_in[5];
  const float* b3 = (const float*)d_in[6];
  const int*   ei = (const int*)d_in[7];
  const int* src = ei;
  const int* dst = ei + NE;
  float* out = (float*)d_out;

  char* w = (char*)d_ws;
  size_t p = 0;
  auto alloc = [&](size_t bytes) -> void* {
    void* r = w + p;
    p += (bytes + 255) & ~(size_t)255;
    return r;
  };
  int*   deg     = (int*)alloc((size_t)NN * 4);
  int*   cur     = (int*)alloc((size_t)NN * 4);
  int*   offs    = (int*)alloc((size_t)NN * 4);
  float* dinv    = (float*)alloc((size_t)NN * 4);
  int*   bsum    = (int*)alloc(1024);
  int*   csr_src = (int*)alloc((size_t)NE * 4);
  float* B1      = (float*)alloc((size_t)NN * DIM * 4);
  float* B2      = (float*)alloc((size_t)NN * DIM * 4);
  (void)ws_size; (void)in_sizes; (void)n_in; (void)out_size;

  hipMemsetAsync(deg, 0, (size_t)NN * 4, stream);
  hipMemsetAsync(cur, 0, (size_t)NN * 4, stream);

  k_deg<<<(NE + 255) / 256, 256, 0, stream>>>(dst, deg);
  k_dinv<<<(NN + 255) / 256, 256, 0, stream>>>(deg, dinv);
  int nb = (NN + SCHUNK - 1) / SCHUNK;  // 98
  k_scan1<<<nb, 256, 0, stream>>>(deg, bsum);
  k_scan2<<<1, 64, 0, stream>>>(bsum, nb);
  k_scan3<<<nb, 256, 0, stream>>>(deg, bsum, offs);
  k_fill<<<(NE + 255) / 256, 256, 0, stream>>>(src, dst, offs, cur, csr_src);

  k_gemm<<<NN / 32, 256, 0, stream>>>(x,  W1, B1);
  k_agg <<<NN, 128, 0, stream>>>(B1, csr_src, offs, deg, dinv, b1, B2, 1);
  k_gemm<<<NN / 32, 256, 0, stream>>>(B2, W2, B1);
  k_agg <<<NN, 128, 0, stream>>>(B1, csr_src, offs, deg, dinv, b2, B2, 1);
  k_gemm<<<NN / 32, 256, 0, stream>>>(B2, W3, B1);
  k_agg <<<NN, 128, 0, stream>>>(B1, csr_src, offs, deg, dinv, b3, B2, 0);
  k_decode<<<(NE * 16 + 255) / 256, 256, 0, stream>>>(B2, src, dst, out);
}

// Round 2
// 1144.376 us; speedup vs baseline: 1.0687x; 1.0687x over previous
//
#include <hip/hip_runtime.h>
#include <math.h>

#define NN 100000
#define NE 1600000
#define DIM 128
#define SCHUNK 1024

// ---------------- degree / norm ----------------
__global__ void k_deg(const int* __restrict__ dst, int* __restrict__ deg) {
  int i = blockIdx.x * blockDim.x + threadIdx.x;
  if (i < NE) atomicAdd(&deg[dst[i]], 1);
}

__global__ void k_dinv(const int* __restrict__ deg, float* __restrict__ dinv) {
  int i = blockIdx.x * blockDim.x + threadIdx.x;
  if (i < NN) dinv[i] = rsqrtf((float)deg[i] + 1.0f);
}

// ---------------- exclusive prefix scan of deg -> offs ----------------
__global__ void k_scan1(const int* __restrict__ deg, int* __restrict__ bsum) {
  __shared__ int sd[256];
  int t = threadIdx.x;
  int base = blockIdx.x * SCHUNK + t * 4;
  int s = 0;
#pragma unroll
  for (int j = 0; j < 4; ++j) { int idx = base + j; if (idx < NN) s += deg[idx]; }
  sd[t] = s; __syncthreads();
  for (int off = 128; off > 0; off >>= 1) {
    if (t < off) sd[t] += sd[t + off];
    __syncthreads();
  }
  if (t == 0) bsum[blockIdx.x] = sd[0];
}

__global__ void k_scan2(int* __restrict__ bsum, int nb) {
  if (threadIdx.x == 0 && blockIdx.x == 0) {
    int run = 0;
    for (int b = 0; b < nb; ++b) { int v = bsum[b]; bsum[b] = run; run += v; }
  }
}

__global__ void k_scan3(const int* __restrict__ deg, const int* __restrict__ bsum,
                        int* __restrict__ offs) {
  __shared__ int ts[256];
  int t = threadIdx.x;
  int base = blockIdx.x * SCHUNK + t * 4;
  int v[4]; int loc = 0;
#pragma unroll
  for (int j = 0; j < 4; ++j) { int idx = base + j; v[j] = (idx < NN) ? deg[idx] : 0; loc += v[j]; }
  ts[t] = loc; __syncthreads();
  for (int off = 1; off < 256; off <<= 1) {
    int x = (t >= off) ? ts[t - off] : 0;
    __syncthreads();
    ts[t] += x;
    __syncthreads();
  }
  int run = bsum[blockIdx.x] + ts[t] - loc;
#pragma unroll
  for (int j = 0; j < 4; ++j) { int idx = base + j; if (idx < NN) offs[idx] = run; run += v[j]; }
}

// fill CSR: src, dst, and original edge id per slot
__global__ void k_fill(const int* __restrict__ src, const int* __restrict__ dst,
                       const int* __restrict__ offs, int* __restrict__ cur,
                       int* __restrict__ csr_src, int* __restrict__ csr_dst,
                       int* __restrict__ csr_eid) {
  int i = blockIdx.x * blockDim.x + threadIdx.x;
  if (i < NE) {
    int d = dst[i];
    int pos = offs[d] + atomicAdd(&cur[d], 1);
    csr_src[pos] = src[i];
    if (csr_dst) csr_dst[pos] = d;
    if (csr_eid) csr_eid[pos] = i;
  }
}

// ---------------- GEMM: C[NN,128] = X[NN,128] @ W[128,128] ----------------
__launch_bounds__(256)
__global__ void k_gemm(const float* __restrict__ X, const float* __restrict__ W,
                       float* __restrict__ C) {
  __shared__ float xs[32][36];
  __shared__ float ws[32][128];
  int t = threadIdx.x;
  int tx = t & 31, ty = t >> 5;
  int row0 = blockIdx.x * 32;
  int c0 = tx * 4;
  float acc[4][4];
#pragma unroll
  for (int i = 0; i < 4; ++i)
#pragma unroll
    for (int j = 0; j < 4; ++j) acc[i][j] = 0.f;

  for (int k0 = 0; k0 < DIM; k0 += 32) {
    int r = t >> 3, cc = (t & 7) * 4;
    *(float4*)&xs[r][cc] = *(const float4*)&X[(size_t)(row0 + r) * DIM + k0 + cc];
#pragma unroll
    for (int i = 0; i < 4; ++i) {
      int kr = ty + i * 8;
      *(float4*)&ws[kr][tx * 4] = *(const float4*)&W[(size_t)(k0 + kr) * DIM + tx * 4];
    }
    __syncthreads();
#pragma unroll
    for (int kk = 0; kk < 32; kk += 4) {
      float4 xv[4], wv[4];
#pragma unroll
      for (int i = 0; i < 4; ++i) xv[i] = *(const float4*)&xs[ty * 4 + i][kk];
#pragma unroll
      for (int j = 0; j < 4; ++j) wv[j] = *(const float4*)&ws[kk + j][c0];
#pragma unroll
      for (int i = 0; i < 4; ++i) {
        acc[i][0] += xv[i].x * wv[0].x + xv[i].y * wv[1].x + xv[i].z * wv[2].x + xv[i].w * wv[3].x;
        acc[i][1] += xv[i].x * wv[0].y + xv[i].y * wv[1].y + xv[i].z * wv[2].y + xv[i].w * wv[3].y;
        acc[i][2] += xv[i].x * wv[0].z + xv[i].y * wv[1].z + xv[i].z * wv[2].z + xv[i].w * wv[3].z;
        acc[i][3] += xv[i].x * wv[0].w + xv[i].y * wv[1].w + xv[i].z * wv[2].w + xv[i].w * wv[3].w;
      }
    }
    __syncthreads();
  }
#pragma unroll
  for (int i = 0; i < 4; ++i) {
    int row = row0 + ty * 4 + i;
    *(float4*)&C[(size_t)row * DIM + c0] = make_float4(acc[i][0], acc[i][1], acc[i][2], acc[i][3]);
  }
}

// ---------------- aggregation ----------------
__global__ void k_agg(const float* __restrict__ h, const int* __restrict__ csr_src,
                      const int* __restrict__ offs, const int* __restrict__ deg,
                      const float* __restrict__ dinv, const float* __restrict__ bias,
                      float* __restrict__ out, int relu) {
  int n = blockIdx.x;
  int c = threadIdx.x;
  float dn = dinv[n];
  int s = offs[n], cnt = deg[n];
  float acc = 0.f;
  for (int i = 0; i < cnt; ++i) {
    int u = csr_src[s + i];
    acc += dinv[u] * h[(size_t)u * DIM + c];
  }
  acc = acc * dn + h[(size_t)n * DIM + c] * (dn * dn) + bias[c];
  out[(size_t)n * DIM + c] = relu ? fmaxf(acc, 0.f) : acc;
}

// ---------------- decode, CSR (dst-sorted) order ----------------
__global__ void k_decode_csr(const float* __restrict__ z, const int* __restrict__ csr_src,
                             const int* __restrict__ csr_dst, const int* __restrict__ csr_eid,
                             float* __restrict__ out) {
  int g = blockIdx.x * blockDim.x + threadIdx.x;
  int l = g & 15;
  int p = g >> 4;
  if (p >= NE) return;
  int s = csr_src[p], d = csr_dst[p], e = csr_eid[p];
  const float4* zs = (const float4*)(z + (size_t)s * DIM);
  const float4* zd = (const float4*)(z + (size_t)d * DIM);
  float4 a0 = zs[l * 2], a1 = zs[l * 2 + 1];
  float4 b0 = zd[l * 2], b1 = zd[l * 2 + 1];
  float p4 = a0.x * b0.x + a0.y * b0.y + a0.z * b0.z + a0.w * b0.w
           + a1.x * b1.x + a1.y * b1.y + a1.z * b1.z + a1.w * b1.w;
#pragma unroll
  for (int off = 8; off >= 1; off >>= 1) p4 += __shfl_xor(p4, off);
  if (l == 0) out[e] = 1.0f / (1.0f + expf(-p4));
}

// fallback: original edge order (if workspace can't fit csr_dst/csr_eid)
__global__ void k_decode(const float* __restrict__ z, const int* __restrict__ src,
                         const int* __restrict__ dst, float* __restrict__ out) {
  int g = blockIdx.x * blockDim.x + threadIdx.x;
  int l = g & 15;
  int e = g >> 4;
  if (e >= NE) return;
  int s = src[e], d = dst[e];
  const float4* zs = (const float4*)(z + (size_t)s * DIM);
  const float4* zd = (const float4*)(z + (size_t)d * DIM);
  float4 a0 = zs[l * 2], a1 = zs[l * 2 + 1];
  float4 b0 = zd[l * 2], b1 = zd[l * 2 + 1];
  float p = a0.x * b0.x + a0.y * b0.y + a0.z * b0.z + a0.w * b0.w
          + a1.x * b1.x + a1.y * b1.y + a1.z * b1.z + a1.w * b1.w;
#pragma unroll
  for (int off = 8; off >= 1; off >>= 1) p += __shfl_xor(p, off);
  if (l == 0) out[e] = 1.0f / (1.0f + expf(-p));
}

extern "C" void kernel_launch(void* const* d_in, const int* in_sizes, int n_in,
                              void* d_out, int out_size, void* d_ws, size_t ws_size,
                              hipStream_t stream) {
  const float* x  = (const float*)d_in[0];
  const float* W1 = (const float*)d_in[1];
  const float* b1 = (const float*)d_in[2];
  const float* W2 = (const float*)d_in[3];
  const float* b2 = (const float*)d_in[4];
  const float* W3 = (const float*)d_in[5];
  const float* b3 = (const float*)d_in[6];
  const int*   ei = (const int*)d_in[7];
  const int* src = ei;
  const int* dst = ei + NE;
  float* out = (float*)d_out;

  char* w = (char*)d_ws;
  size_t p = 0;
  auto alloc = [&](size_t bytes) -> void* {
    void* r = w + p;
    p += (bytes + 255) & ~(size_t)255;
    return r;
  };
  int*   deg     = (int*)alloc((size_t)NN * 4);
  int*   cur     = (int*)alloc((size_t)NN * 4);
  int*   offs    = (int*)alloc((size_t)NN * 4);
  float* dinv    = (float*)alloc((size_t)NN * 4);
  int*   bsum    = (int*)alloc(1024);
  int*   csr_src = (int*)alloc((size_t)NE * 4);
  float* B1      = (float*)alloc((size_t)NN * DIM * 4);
  float* B2      = (float*)alloc((size_t)NN * DIM * 4);
  size_t base_needed = p;
  int* csr_dst = nullptr;
  int* csr_eid = nullptr;
  if (ws_size >= base_needed + 2 * ((size_t)NE * 4 + 256)) {
    csr_dst = (int*)alloc((size_t)NE * 4);
    csr_eid = (int*)alloc((size_t)NE * 4);
  }
  (void)in_sizes; (void)n_in; (void)out_size;

  hipMemsetAsync(deg, 0, (size_t)NN * 4, stream);
  hipMemsetAsync(cur, 0, (size_t)NN * 4, stream);

  k_deg<<<(NE + 255) / 256, 256, 0, stream>>>(dst, deg);
  k_dinv<<<(NN + 255) / 256, 256, 0, stream>>>(deg, dinv);
  int nb = (NN + SCHUNK - 1) / SCHUNK;  // 98
  k_scan1<<<nb, 256, 0, stream>>>(deg, bsum);
  k_scan2<<<1, 64, 0, stream>>>(bsum, nb);
  k_scan3<<<nb, 256, 0, stream>>>(deg, bsum, offs);
  k_fill<<<(NE + 255) / 256, 256, 0, stream>>>(src, dst, offs, cur, csr_src, csr_dst, csr_eid);

  k_gemm<<<NN / 32, 256, 0, stream>>>(x,  W1, B1);
  k_agg <<<NN, 128, 0, stream>>>(B1, csr_src, offs, deg, dinv, b1, B2, 1);
  k_gemm<<<NN / 32, 256, 0, stream>>>(B2, W2, B1);
  k_agg <<<NN, 128, 0, stream>>>(B1, csr_src, offs, deg, dinv, b2, B2, 1);
  k_gemm<<<NN / 32, 256, 0, stream>>>(B2, W3, B1);
  k_agg <<<NN, 128, 0, stream>>>(B1, csr_src, offs, deg, dinv, b3, B2, 0);

  if (csr_dst && csr_eid) {
    k_decode_csr<<<(NE * 16 + 255) / 256, 256, 0, stream>>>(B2, csr_src, csr_dst, csr_eid, out);
  } else {
    k_decode<<<(NE * 16 + 255) / 256, 256, 0, stream>>>(B2, src, dst, out);
  }
}

// Round 3
// 955.247 us; speedup vs baseline: 1.2803x; 1.1980x over previous
//
#include <hip/hip_runtime.h>
#include <math.h>

#define NN 100000
#define NE 1600000
#define DIM 128
#define SCHUNK 1024

// ---------------- degree / norm ----------------
__global__ void k_deg(const int* __restrict__ dst, int* __restrict__ deg) {
  int i = blockIdx.x * blockDim.x + threadIdx.x;
  if (i < NE) atomicAdd(&deg[dst[i]], 1);
}

__global__ void k_dinv(const int* __restrict__ deg, float* __restrict__ dinv) {
  int i = blockIdx.x * blockDim.x + threadIdx.x;
  if (i < NN) dinv[i] = rsqrtf((float)deg[i] + 1.0f);
}

// ---------------- exclusive prefix scan of deg -> offs ----------------
__global__ void k_scan1(const int* __restrict__ deg, int* __restrict__ bsum) {
  __shared__ int sd[256];
  int t = threadIdx.x;
  int base = blockIdx.x * SCHUNK + t * 4;
  int s = 0;
#pragma unroll
  for (int j = 0; j < 4; ++j) { int idx = base + j; if (idx < NN) s += deg[idx]; }
  sd[t] = s; __syncthreads();
  for (int off = 128; off > 0; off >>= 1) {
    if (t < off) sd[t] += sd[t + off];
    __syncthreads();
  }
  if (t == 0) bsum[blockIdx.x] = sd[0];
}

__global__ void k_scan2(int* __restrict__ bsum, int nb) {
  if (threadIdx.x == 0 && blockIdx.x == 0) {
    int run = 0;
    for (int b = 0; b < nb; ++b) { int v = bsum[b]; bsum[b] = run; run += v; }
  }
}

__global__ void k_scan3(const int* __restrict__ deg, const int* __restrict__ bsum,
                        int* __restrict__ offs) {
  __shared__ int ts[256];
  int t = threadIdx.x;
  int base = blockIdx.x * SCHUNK + t * 4;
  int v[4]; int loc = 0;
#pragma unroll
  for (int j = 0; j < 4; ++j) { int idx = base + j; v[j] = (idx < NN) ? deg[idx] : 0; loc += v[j]; }
  ts[t] = loc; __syncthreads();
  for (int off = 1; off < 256; off <<= 1) {
    int x = (t >= off) ? ts[t - off] : 0;
    __syncthreads();
    ts[t] += x;
    __syncthreads();
  }
  int run = bsum[blockIdx.x] + ts[t] - loc;
#pragma unroll
  for (int j = 0; j < 4; ++j) { int idx = base + j; if (idx < NN) offs[idx] = run; run += v[j]; }
}

// fill CSR: src, dst, and original edge id per slot
__global__ void k_fill(const int* __restrict__ src, const int* __restrict__ dst,
                       const int* __restrict__ offs, int* __restrict__ cur,
                       int* __restrict__ csr_src, int* __restrict__ csr_dst,
                       int* __restrict__ csr_eid) {
  int i = blockIdx.x * blockDim.x + threadIdx.x;
  if (i < NE) {
    int d = dst[i];
    int pos = offs[d] + atomicAdd(&cur[d], 1);
    csr_src[pos] = src[i];
    if (csr_dst) csr_dst[pos] = d;
    if (csr_eid) csr_eid[pos] = i;
  }
}

// ---------------- GEMM: C[n] = dinv[n] * (X[n] @ W), 64-row tile ----------------
__launch_bounds__(256)
__global__ void k_gemm(const float* __restrict__ X, const float* __restrict__ W,
                       const float* __restrict__ dinv, float* __restrict__ C) {
  __shared__ float xs[64][36];     // 64 rows x 32 k (padded)
  __shared__ float ws[32][128];    // 32 k x 128 cols
  int t = threadIdx.x;
  int tx = t & 31, ty = t >> 5;    // tx: col group (4 cols), ty in [0,8): row group (8 rows)
  int row0 = blockIdx.x * 64;
  int c0 = tx * 4;
  float acc[8][4];
#pragma unroll
  for (int i = 0; i < 8; ++i)
#pragma unroll
    for (int j = 0; j < 4; ++j) acc[i][j] = 0.f;

  for (int k0 = 0; k0 < DIM; k0 += 32) {
    int r = t >> 3, cc = (t & 7) * 4;       // r in [0,32), cc in [0,32)
    int r1 = row0 + r, r2 = row0 + r + 32;
    r1 = r1 < NN ? r1 : NN - 1;
    r2 = r2 < NN ? r2 : NN - 1;
    *(float4*)&xs[r][cc]      = *(const float4*)&X[(size_t)r1 * DIM + k0 + cc];
    *(float4*)&xs[r + 32][cc] = *(const float4*)&X[(size_t)r2 * DIM + k0 + cc];
#pragma unroll
    for (int i = 0; i < 4; ++i) {
      int kr = ty + i * 8;
      *(float4*)&ws[kr][tx * 4] = *(const float4*)&W[(size_t)(k0 + kr) * DIM + tx * 4];
    }
    __syncthreads();
#pragma unroll
    for (int kk = 0; kk < 32; kk += 4) {
      float4 wv[4];
#pragma unroll
      for (int j = 0; j < 4; ++j) wv[j] = *(const float4*)&ws[kk + j][c0];
#pragma unroll
      for (int i = 0; i < 8; ++i) {
        float4 xv = *(const float4*)&xs[ty * 8 + i][kk];
        acc[i][0] += xv.x * wv[0].x + xv.y * wv[1].x + xv.z * wv[2].x + xv.w * wv[3].x;
        acc[i][1] += xv.x * wv[0].y + xv.y * wv[1].y + xv.z * wv[2].y + xv.w * wv[3].y;
        acc[i][2] += xv.x * wv[0].z + xv.y * wv[1].z + xv.z * wv[2].z + xv.w * wv[3].z;
        acc[i][3] += xv.x * wv[0].w + xv.y * wv[1].w + xv.z * wv[2].w + xv.w * wv[3].w;
      }
    }
    __syncthreads();
  }
#pragma unroll
  for (int i = 0; i < 8; ++i) {
    int row = row0 + ty * 8 + i;
    if (row < NN) {
      float dv = dinv[row];
      *(float4*)&C[(size_t)row * DIM + c0] =
          make_float4(dv * acc[i][0], dv * acc[i][1], dv * acc[i][2], dv * acc[i][3]);
    }
  }
}

// ---------------- aggregation on premultiplied h': out = dn*(sum h'[u] + h'[n]) + b ----
// 256 threads = 8 groups of 32 lanes; group owns one node; lane owns 4 channels.
__launch_bounds__(256)
__global__ void k_agg(const float* __restrict__ hp, const int* __restrict__ csr_src,
                      const int* __restrict__ offs, const int* __restrict__ deg,
                      const float* __restrict__ dinv, const float* __restrict__ bias,
                      float* __restrict__ out, int relu) {
  int t = threadIdx.x;
  int g = t >> 5, l = t & 31;
  int n = blockIdx.x * 8 + g;          // NN/8 exact
  float dn = dinv[n];
  int s = offs[n], cnt = deg[n];
  const float4* hp4 = (const float4*)hp;
  float4 acc = make_float4(0.f, 0.f, 0.f, 0.f);
  int i = 0;
  for (; i + 4 <= cnt; i += 4) {
    int u0 = csr_src[s + i];
    int u1 = csr_src[s + i + 1];
    int u2 = csr_src[s + i + 2];
    int u3 = csr_src[s + i + 3];
    float4 v0 = hp4[(size_t)u0 * 32 + l];
    float4 v1 = hp4[(size_t)u1 * 32 + l];
    float4 v2 = hp4[(size_t)u2 * 32 + l];
    float4 v3 = hp4[(size_t)u3 * 32 + l];
    acc.x += (v0.x + v1.x) + (v2.x + v3.x);
    acc.y += (v0.y + v1.y) + (v2.y + v3.y);
    acc.z += (v0.z + v1.z) + (v2.z + v3.z);
    acc.w += (v0.w + v1.w) + (v2.w + v3.w);
  }
  for (; i < cnt; ++i) {
    int u = csr_src[s + i];
    float4 v = hp4[(size_t)u * 32 + l];
    acc.x += v.x; acc.y += v.y; acc.z += v.z; acc.w += v.w;
  }
  float4 self = hp4[(size_t)n * 32 + l];
  float4 bb = ((const float4*)bias)[l];
  float4 r;
  r.x = dn * (acc.x + self.x) + bb.x;
  r.y = dn * (acc.y + self.y) + bb.y;
  r.z = dn * (acc.z + self.z) + bb.z;
  r.w = dn * (acc.w + self.w) + bb.w;
  if (relu) {
    r.x = fmaxf(r.x, 0.f); r.y = fmaxf(r.y, 0.f);
    r.z = fmaxf(r.z, 0.f); r.w = fmaxf(r.w, 0.f);
  }
  ((float4*)out)[(size_t)n * 32 + l] = r;
}

// ---------------- decode, CSR (dst-sorted) order ----------------
__global__ void k_decode_csr(const float* __restrict__ z, const int* __restrict__ csr_src,
                             const int* __restrict__ csr_dst, const int* __restrict__ csr_eid,
                             float* __restrict__ out) {
  int g = blockIdx.x * blockDim.x + threadIdx.x;
  int l = g & 15;
  int p = g >> 4;
  if (p >= NE) return;
  int s = csr_src[p], d = csr_dst[p], e = csr_eid[p];
  const float4* zs = (const float4*)(z + (size_t)s * DIM);
  const float4* zd = (const float4*)(z + (size_t)d * DIM);
  float4 a0 = zs[l * 2], a1 = zs[l * 2 + 1];
  float4 b0 = zd[l * 2], b1 = zd[l * 2 + 1];
  float p4 = a0.x * b0.x + a0.y * b0.y + a0.z * b0.z + a0.w * b0.w
           + a1.x * b1.x + a1.y * b1.y + a1.z * b1.z + a1.w * b1.w;
#pragma unroll
  for (int off = 8; off >= 1; off >>= 1) p4 += __shfl_xor(p4, off);
  if (l == 0) out[e] = 1.0f / (1.0f + expf(-p4));
}

// fallback: original edge order (if workspace can't fit csr_dst/csr_eid)
__global__ void k_decode(const float* __restrict__ z, const int* __restrict__ src,
                         const int* __restrict__ dst, float* __restrict__ out) {
  int g = blockIdx.x * blockDim.x + threadIdx.x;
  int l = g & 15;
  int e = g >> 4;
  if (e >= NE) return;
  int s = src[e], d = dst[e];
  const float4* zs = (const float4*)(z + (size_t)s * DIM);
  const float4* zd = (const float4*)(z + (size_t)d * DIM);
  float4 a0 = zs[l * 2], a1 = zs[l * 2 + 1];
  float4 b0 = zd[l * 2], b1 = zd[l * 2 + 1];
  float p = a0.x * b0.x + a0.y * b0.y + a0.z * b0.z + a0.w * b0.w
          + a1.x * b1.x + a1.y * b1.y + a1.z * b1.z + a1.w * b1.w;
#pragma unroll
  for (int off = 8; off >= 1; off >>= 1) p += __shfl_xor(p, off);
  if (l == 0) out[e] = 1.0f / (1.0f + expf(-p));
}

extern "C" void kernel_launch(void* const* d_in, const int* in_sizes, int n_in,
                              void* d_out, int out_size, void* d_ws, size_t ws_size,
                              hipStream_t stream) {
  const float* x  = (const float*)d_in[0];
  const float* W1 = (const float*)d_in[1];
  const float* b1 = (const float*)d_in[2];
  const float* W2 = (const float*)d_in[3];
  const float* b2 = (const float*)d_in[4];
  const float* W3 = (const float*)d_in[5];
  const float* b3 = (const float*)d_in[6];
  const int*   ei = (const int*)d_in[7];
  const int* src = ei;
  const int* dst = ei + NE;
  float* out = (float*)d_out;

  char* w = (char*)d_ws;
  size_t p = 0;
  auto alloc = [&](size_t bytes) -> void* {
    void* r = w + p;
    p += (bytes + 255) & ~(size_t)255;
    return r;
  };
  int*   deg     = (int*)alloc((size_t)NN * 4);
  int*   cur     = (int*)alloc((size_t)NN * 4);
  int*   offs    = (int*)alloc((size_t)NN * 4);
  float* dinv    = (float*)alloc((size_t)NN * 4);
  int*   bsum    = (int*)alloc(1024);
  int*   csr_src = (int*)alloc((size_t)NE * 4);
  float* B1      = (float*)alloc((size_t)NN * DIM * 4);
  float* B2      = (float*)alloc((size_t)NN * DIM * 4);
  size_t base_needed = p;
  int* csr_dst = nullptr;
  int* csr_eid = nullptr;
  if (ws_size >= base_needed + 2 * ((size_t)NE * 4 + 256)) {
    csr_dst = (int*)alloc((size_t)NE * 4);
    csr_eid = (int*)alloc((size_t)NE * 4);
  }
  (void)in_sizes; (void)n_in; (void)out_size;

  hipMemsetAsync(deg, 0, (size_t)NN * 4, stream);
  hipMemsetAsync(cur, 0, (size_t)NN * 4, stream);

  k_deg<<<(NE + 255) / 256, 256, 0, stream>>>(dst, deg);
  k_dinv<<<(NN + 255) / 256, 256, 0, stream>>>(deg, dinv);
  int nb = (NN + SCHUNK - 1) / SCHUNK;  // 98
  k_scan1<<<nb, 256, 0, stream>>>(deg, bsum);
  k_scan2<<<1, 64, 0, stream>>>(bsum, nb);
  k_scan3<<<nb, 256, 0, stream>>>(deg, bsum, offs);
  k_fill<<<(NE + 255) / 256, 256, 0, stream>>>(src, dst, offs, cur, csr_src, csr_dst, csr_eid);

  int gb = (NN + 63) / 64;  // 1563
  k_gemm<<<gb, 256, 0, stream>>>(x,  W1, dinv, B1);
  k_agg <<<NN / 8, 256, 0, stream>>>(B1, csr_src, offs, deg, dinv, b1, B2, 1);
  k_gemm<<<gb, 256, 0, stream>>>(B2, W2, dinv, B1);
  k_agg <<<NN / 8, 256, 0, stream>>>(B1, csr_src, offs, deg, dinv, b2, B2, 1);
  k_gemm<<<gb, 256, 0, stream>>>(B2, W3, dinv, B1);
  k_agg <<<NN / 8, 256, 0, stream>>>(B1, csr_src, offs, deg, dinv, b3, B2, 0);

  if (csr_dst && csr_eid) {
    k_decode_csr<<<(NE * 16 + 255) / 256, 256, 0, stream>>>(B2, csr_src, csr_dst, csr_eid, out);
  } else {
    k_decode<<<(NE * 16 + 255) / 256, 256, 0, stream>>>(B2, src, dst, out);
  }
}

// Round 4
// 771.562 us; speedup vs baseline: 1.5851x; 1.2381x over previous
//
#include <hip/hip_runtime.h>
#include <math.h>

#define NN 100000
#define NE 1600000
#define DIM 128
#define SCHUNK 1024

typedef unsigned short u16;
typedef unsigned int u32;

__device__ inline u16 f2bf(float f) {
  union { float f; u32 u; } v; v.f = f;
  u32 r = v.u + 0x7FFF + ((v.u >> 16) & 1);   // round-to-nearest-even
  return (u16)(r >> 16);
}
__device__ inline float bflo(u32 u) { union { u32 u; float f; } v; v.u = u << 16; return v.f; }
__device__ inline float bfhi(u32 u) { union { u32 u; float f; } v; v.u = u & 0xFFFF0000u; return v.f; }

// ---------------- degree / norm ----------------
__global__ void k_deg(const int* __restrict__ dst, int* __restrict__ deg) {
  int i = blockIdx.x * blockDim.x + threadIdx.x;
  if (i < NE) atomicAdd(&deg[dst[i]], 1);
}

__global__ void k_dinv(const int* __restrict__ deg, float* __restrict__ dinv) {
  int i = blockIdx.x * blockDim.x + threadIdx.x;
  if (i < NN) dinv[i] = rsqrtf((float)deg[i] + 1.0f);
}

// ---------------- exclusive prefix scan of deg -> offs ----------------
__global__ void k_scan1(const int* __restrict__ deg, int* __restrict__ bsum) {
  __shared__ int sd[256];
  int t = threadIdx.x;
  int base = blockIdx.x * SCHUNK + t * 4;
  int s = 0;
#pragma unroll
  for (int j = 0; j < 4; ++j) { int idx = base + j; if (idx < NN) s += deg[idx]; }
  sd[t] = s; __syncthreads();
  for (int off = 128; off > 0; off >>= 1) {
    if (t < off) sd[t] += sd[t + off];
    __syncthreads();
  }
  if (t == 0) bsum[blockIdx.x] = sd[0];
}

__global__ void k_scan2(int* __restrict__ bsum, int nb) {
  if (threadIdx.x == 0 && blockIdx.x == 0) {
    int run = 0;
    for (int b = 0; b < nb; ++b) { int v = bsum[b]; bsum[b] = run; run += v; }
  }
}

__global__ void k_scan3(const int* __restrict__ deg, const int* __restrict__ bsum,
                        int* __restrict__ offs) {
  __shared__ int ts[256];
  int t = threadIdx.x;
  int base = blockIdx.x * SCHUNK + t * 4;
  int v[4]; int loc = 0;
#pragma unroll
  for (int j = 0; j < 4; ++j) { int idx = base + j; v[j] = (idx < NN) ? deg[idx] : 0; loc += v[j]; }
  ts[t] = loc; __syncthreads();
  for (int off = 1; off < 256; off <<= 1) {
    int x = (t >= off) ? ts[t - off] : 0;
    __syncthreads();
    ts[t] += x;
    __syncthreads();
  }
  int run = bsum[blockIdx.x] + ts[t] - loc;
#pragma unroll
  for (int j = 0; j < 4; ++j) { int idx = base + j; if (idx < NN) offs[idx] = run; run += v[j]; }
}

// fill CSR: src, dst, and original edge id per slot
__global__ void k_fill(const int* __restrict__ src, const int* __restrict__ dst,
                       const int* __restrict__ offs, int* __restrict__ cur,
                       int* __restrict__ csr_src, int* __restrict__ csr_dst,
                       int* __restrict__ csr_eid) {
  int i = blockIdx.x * blockDim.x + threadIdx.x;
  if (i < NE) {
    int d = dst[i];
    int pos = offs[d] + atomicAdd(&cur[d], 1);
    csr_src[pos] = src[i];
    csr_dst[pos] = d;
    csr_eid[pos] = i;
  }
}

// ---------------- GEMM: hp[n] = bf16( dinv[n] * (X[n] @ W) ), 64-row tile ----------------
__launch_bounds__(256)
__global__ void k_gemm(const float* __restrict__ X, const float* __restrict__ W,
                       const float* __restrict__ dinv, u16* __restrict__ hp) {
  __shared__ float xs[64][36];
  __shared__ float ws[32][128];
  int t = threadIdx.x;
  int tx = t & 31, ty = t >> 5;
  int row0 = blockIdx.x * 64;
  int c0 = tx * 4;
  float acc[8][4];
#pragma unroll
  for (int i = 0; i < 8; ++i)
#pragma unroll
    for (int j = 0; j < 4; ++j) acc[i][j] = 0.f;

  for (int k0 = 0; k0 < DIM; k0 += 32) {
    int r = t >> 3, cc = (t & 7) * 4;
    int r1 = row0 + r, r2 = row0 + r + 32;
    r1 = r1 < NN ? r1 : NN - 1;
    r2 = r2 < NN ? r2 : NN - 1;
    *(float4*)&xs[r][cc]      = *(const float4*)&X[(size_t)r1 * DIM + k0 + cc];
    *(float4*)&xs[r + 32][cc] = *(const float4*)&X[(size_t)r2 * DIM + k0 + cc];
#pragma unroll
    for (int i = 0; i < 4; ++i) {
      int kr = ty + i * 8;
      *(float4*)&ws[kr][tx * 4] = *(const float4*)&W[(size_t)(k0 + kr) * DIM + tx * 4];
    }
    __syncthreads();
#pragma unroll
    for (int kk = 0; kk < 32; kk += 4) {
      float4 wv[4];
#pragma unroll
      for (int j = 0; j < 4; ++j) wv[j] = *(const float4*)&ws[kk + j][c0];
#pragma unroll
      for (int i = 0; i < 8; ++i) {
        float4 xv = *(const float4*)&xs[ty * 8 + i][kk];
        acc[i][0] += xv.x * wv[0].x + xv.y * wv[1].x + xv.z * wv[2].x + xv.w * wv[3].x;
        acc[i][1] += xv.x * wv[0].y + xv.y * wv[1].y + xv.z * wv[2].y + xv.w * wv[3].y;
        acc[i][2] += xv.x * wv[0].z + xv.y * wv[1].z + xv.z * wv[2].z + xv.w * wv[3].z;
        acc[i][3] += xv.x * wv[0].w + xv.y * wv[1].w + xv.z * wv[2].w + xv.w * wv[3].w;
      }
    }
    __syncthreads();
  }
#pragma unroll
  for (int i = 0; i < 8; ++i) {
    int row = row0 + ty * 8 + i;
    if (row < NN) {
      float dv = dinv[row];
      ushort4 o;
      o.x = f2bf(dv * acc[i][0]);
      o.y = f2bf(dv * acc[i][1]);
      o.z = f2bf(dv * acc[i][2]);
      o.w = f2bf(dv * acc[i][3]);
      *(ushort4*)&hp[(size_t)row * DIM + c0] = o;
    }
  }
}

// ---------------- aggregation on bf16 h': out = dn*(sum h'[u] + h'[n]) + b ----------------
// 256 threads = 8 groups of 32 lanes; group owns one node; lane owns 4 channels (8 B bf16).
__launch_bounds__(256)
__global__ void k_agg(const u16* __restrict__ hp, const int* __restrict__ csr_src,
                      const int* __restrict__ offs, const int* __restrict__ deg,
                      const float* __restrict__ dinv, const float* __restrict__ bias,
                      float* __restrict__ outf, u16* __restrict__ outb, int relu) {
  int t = threadIdx.x;
  int g = t >> 5, l = t & 31;
  int n = blockIdx.x * 8 + g;          // NN/8 exact
  float dn = dinv[n];
  int s = offs[n], cnt = deg[n];
  const uint2* hp2 = (const uint2*)hp;   // 4 bf16 per uint2, 32 per row
  float a0 = 0.f, a1 = 0.f, a2 = 0.f, a3 = 0.f;
  int i = 0;
  for (; i + 4 <= cnt; i += 4) {
    int u0 = csr_src[s + i];
    int u1 = csr_src[s + i + 1];
    int u2 = csr_src[s + i + 2];
    int u3 = csr_src[s + i + 3];
    uint2 v0 = hp2[(size_t)u0 * 32 + l];
    uint2 v1 = hp2[(size_t)u1 * 32 + l];
    uint2 v2 = hp2[(size_t)u2 * 32 + l];
    uint2 v3 = hp2[(size_t)u3 * 32 + l];
    a0 += (bflo(v0.x) + bflo(v1.x)) + (bflo(v2.x) + bflo(v3.x));
    a1 += (bfhi(v0.x) + bfhi(v1.x)) + (bfhi(v2.x) + bfhi(v3.x));
    a2 += (bflo(v0.y) + bflo(v1.y)) + (bflo(v2.y) + bflo(v3.y));
    a3 += (bfhi(v0.y) + bfhi(v1.y)) + (bfhi(v2.y) + bfhi(v3.y));
  }
  for (; i < cnt; ++i) {
    int u = csr_src[s + i];
    uint2 v = hp2[(size_t)u * 32 + l];
    a0 += bflo(v.x); a1 += bfhi(v.x); a2 += bflo(v.y); a3 += bfhi(v.y);
  }
  uint2 sv = hp2[(size_t)n * 32 + l];
  float4 bb = ((const float4*)bias)[l];
  float r0 = dn * (a0 + bflo(sv.x)) + bb.x;
  float r1 = dn * (a1 + bfhi(sv.x)) + bb.y;
  float r2 = dn * (a2 + bflo(sv.y)) + bb.z;
  float r3 = dn * (a3 + bfhi(sv.y)) + bb.w;
  if (relu) {
    r0 = fmaxf(r0, 0.f); r1 = fmaxf(r1, 0.f);
    r2 = fmaxf(r2, 0.f); r3 = fmaxf(r3, 0.f);
  }
  if (outf) {
    ((float4*)outf)[(size_t)n * 32 + l] = make_float4(r0, r1, r2, r3);
  } else {
    ushort4 o; o.x = f2bf(r0); o.y = f2bf(r1); o.z = f2bf(r2); o.w = f2bf(r3);
    *(ushort4*)&outb[(size_t)n * DIM + l * 4] = o;
  }
}

// ---------------- decode on bf16 z, CSR (dst-sorted) order ----------------
// 16 lanes per edge; lane reads 16 B (8 bf16) from each endpoint row (256 B rows).
__global__ void k_decode_csr(const u16* __restrict__ z, const int* __restrict__ csr_src,
                             const int* __restrict__ csr_dst, const int* __restrict__ csr_eid,
                             float* __restrict__ out) {
  int g = blockIdx.x * blockDim.x + threadIdx.x;
  int l = g & 15;
  int p = g >> 4;
  if (p >= NE) return;
  int s = csr_src[p], d = csr_dst[p], e = csr_eid[p];
  const uint4* z4 = (const uint4*)z;     // 8 bf16 per uint4, 16 per row
  uint4 a = z4[(size_t)s * 16 + l];
  uint4 b = z4[(size_t)d * 16 + l];
  float acc = bflo(a.x) * bflo(b.x) + bfhi(a.x) * bfhi(b.x)
            + bflo(a.y) * bflo(b.y) + bfhi(a.y) * bfhi(b.y)
            + bflo(a.z) * bflo(b.z) + bfhi(a.z) * bfhi(b.z)
            + bflo(a.w) * bflo(b.w) + bfhi(a.w) * bfhi(b.w);
#pragma unroll
  for (int off = 8; off >= 1; off >>= 1) acc += __shfl_xor(acc, off);
  if (l == 0) out[e] = 1.0f / (1.0f + expf(-acc));
}

extern "C" void kernel_launch(void* const* d_in, const int* in_sizes, int n_in,
                              void* d_out, int out_size, void* d_ws, size_t ws_size,
                              hipStream_t stream) {
  const float* x  = (const float*)d_in[0];
  const float* W1 = (const float*)d_in[1];
  const float* b1 = (const float*)d_in[2];
  const float* W2 = (const float*)d_in[3];
  const float* b2 = (const float*)d_in[4];
  const float* W3 = (const float*)d_in[5];
  const float* b3 = (const float*)d_in[6];
  const int*   ei = (const int*)d_in[7];
  const int* src = ei;
  const int* dst = ei + NE;
  float* out = (float*)d_out;

  char* w = (char*)d_ws;
  size_t p = 0;
  auto alloc = [&](size_t bytes) -> void* {
    void* r = w + p;
    p += (bytes + 255) & ~(size_t)255;
    return r;
  };
  int*   deg     = (int*)alloc((size_t)NN * 4);
  int*   cur     = (int*)alloc((size_t)NN * 4);
  int*   offs    = (int*)alloc((size_t)NN * 4);
  float* dinv    = (float*)alloc((size_t)NN * 4);
  int*   bsum    = (int*)alloc(1024);
  int*   csr_src = (int*)alloc((size_t)NE * 4);
  int*   csr_dst = (int*)alloc((size_t)NE * 4);
  int*   csr_eid = (int*)alloc((size_t)NE * 4);
  float* B2      = (float*)alloc((size_t)NN * DIM * 4);   // fp32 agg output (GEMM input)
  u16*   hp      = (u16*)alloc((size_t)NN * DIM * 2);     // bf16 premultiplied GEMM output
  u16*   zb      = (u16*)alloc((size_t)NN * DIM * 2);     // bf16 final embeddings for decode
  (void)in_sizes; (void)n_in; (void)out_size; (void)ws_size;

  hipMemsetAsync(deg, 0, (size_t)NN * 4, stream);
  hipMemsetAsync(cur, 0, (size_t)NN * 4, stream);

  k_deg<<<(NE + 255) / 256, 256, 0, stream>>>(dst, deg);
  k_dinv<<<(NN + 255) / 256, 256, 0, stream>>>(deg, dinv);
  int nb = (NN + SCHUNK - 1) / SCHUNK;  // 98
  k_scan1<<<nb, 256, 0, stream>>>(deg, bsum);
  k_scan2<<<1, 64, 0, stream>>>(bsum, nb);
  k_scan3<<<nb, 256, 0, stream>>>(deg, bsum, offs);
  k_fill<<<(NE + 255) / 256, 256, 0, stream>>>(src, dst, offs, cur, csr_src, csr_dst, csr_eid);

  int gb = (NN + 63) / 64;  // 1563
  k_gemm<<<gb, 256, 0, stream>>>(x,  W1, dinv, hp);
  k_agg <<<NN / 8, 256, 0, stream>>>(hp, csr_src, offs, deg, dinv, b1, B2, nullptr, 1);
  k_gemm<<<gb, 256, 0, stream>>>(B2, W2, dinv, hp);
  k_agg <<<NN / 8, 256, 0, stream>>>(hp, csr_src, offs, deg, dinv, b2, B2, nullptr, 1);
  k_gemm<<<gb, 256, 0, stream>>>(B2, W3, dinv, hp);
  k_agg <<<NN / 8, 256, 0, stream>>>(hp, csr_src, offs, deg, dinv, b3, nullptr, zb, 0);

  k_decode_csr<<<(NE * 16 + 255) / 256, 256, 0, stream>>>(zb, csr_src, csr_dst, csr_eid, out);
}

// Round 5
// 510.996 us; speedup vs baseline: 2.3934x; 1.5099x over previous
//
#include <hip/hip_runtime.h>
#include <math.h>

#define NN 100000
#define NE 1600000
#define DIM 128
#define SCHUNK 1024

typedef unsigned short u16;
typedef unsigned int u32;
typedef __attribute__((ext_vector_type(8))) short bf16x8;
typedef __attribute__((ext_vector_type(4))) float f32x4;

__device__ inline u16 f2bf(float f) {
  union { float f; u32 u; } v; v.f = f;
  u32 r = v.u + 0x7FFF + ((v.u >> 16) & 1);   // round-to-nearest-even
  return (u16)(r >> 16);
}
__device__ inline float bflo(u32 u) { union { u32 u; float f; } v; v.u = u << 16; return v.f; }
__device__ inline float bfhi(u32 u) { union { u32 u; float f; } v; v.u = u & 0xFFFF0000u; return v.f; }

// ---------------- degree / norm ----------------
__global__ void k_deg(const int* __restrict__ dst, int* __restrict__ deg) {
  int i = blockIdx.x * blockDim.x + threadIdx.x;
  if (i < NE) atomicAdd(&deg[dst[i]], 1);
}

__global__ void k_dinv(const int* __restrict__ deg, float* __restrict__ dinv) {
  int i = blockIdx.x * blockDim.x + threadIdx.x;
  if (i < NN) dinv[i] = rsqrtf((float)deg[i] + 1.0f);
}

// ---------------- exclusive prefix scan of deg -> offs ----------------
__global__ void k_scan1(const int* __restrict__ deg, int* __restrict__ bsum) {
  __shared__ int sd[256];
  int t = threadIdx.x;
  int base = blockIdx.x * SCHUNK + t * 4;
  int s = 0;
#pragma unroll
  for (int j = 0; j < 4; ++j) { int idx = base + j; if (idx < NN) s += deg[idx]; }
  sd[t] = s; __syncthreads();
  for (int off = 128; off > 0; off >>= 1) {
    if (t < off) sd[t] += sd[t + off];
    __syncthreads();
  }
  if (t == 0) bsum[blockIdx.x] = sd[0];
}

__global__ void k_scan2(int* __restrict__ bsum, int nb) {
  if (threadIdx.x == 0 && blockIdx.x == 0) {
    int run = 0;
    for (int b = 0; b < nb; ++b) { int v = bsum[b]; bsum[b] = run; run += v; }
  }
}

__global__ void k_scan3(const int* __restrict__ deg, const int* __restrict__ bsum,
                        int* __restrict__ offs) {
  __shared__ int ts[256];
  int t = threadIdx.x;
  int base = blockIdx.x * SCHUNK + t * 4;
  int v[4]; int loc = 0;
#pragma unroll
  for (int j = 0; j < 4; ++j) { int idx = base + j; v[j] = (idx < NN) ? deg[idx] : 0; loc += v[j]; }
  ts[t] = loc; __syncthreads();
  for (int off = 1; off < 256; off <<= 1) {
    int x = (t >= off) ? ts[t - off] : 0;
    __syncthreads();
    ts[t] += x;
    __syncthreads();
  }
  int run = bsum[blockIdx.x] + ts[t] - loc;
#pragma unroll
  for (int j = 0; j < 4; ++j) { int idx = base + j; if (idx < NN) offs[idx] = run; run += v[j]; }
}

// fill CSR: src, dst, and original edge id per slot
__global__ void k_fill(const int* __restrict__ src, const int* __restrict__ dst,
                       const int* __restrict__ offs, int* __restrict__ cur,
                       int* __restrict__ csr_src, int* __restrict__ csr_dst,
                       int* __restrict__ csr_eid) {
  int i = blockIdx.x * blockDim.x + threadIdx.x;
  if (i < NE) {
    int d = dst[i];
    int pos = offs[d] + atomicAdd(&cur[d], 1);
    csr_src[pos] = src[i];
    csr_dst[pos] = d;
    csr_eid[pos] = i;
  }
}

// ---------------- fp32 -> bf16 convert (for x) ----------------
__global__ void k_tobf(const float* __restrict__ in, u16* __restrict__ out, int n4) {
  int i = blockIdx.x * blockDim.x + threadIdx.x;
  if (i < n4) {
    float4 v = ((const float4*)in)[i];
    ushort4 o;
    o.x = f2bf(v.x); o.y = f2bf(v.y); o.z = f2bf(v.z); o.w = f2bf(v.w);
    ((ushort4*)out)[i] = o;
  }
}

// ---------------- pack W (fp32 row-major [128][128]) into MFMA B-frag order ----------------
// Wp flat = ct*2048 + ks*512 + kb*128 + j*8 + b  <=  W[ks*32+kb*8+b][ct*16+j]
__global__ void k_pack(const float* __restrict__ W, u16* __restrict__ Wp) {
  int tid = blockIdx.x * blockDim.x + threadIdx.x;   // 16384
  int b = tid & 7, j = (tid >> 3) & 15, kb = (tid >> 7) & 3, ks = (tid >> 9) & 3, ct = tid >> 11;
  int k = ks * 32 + kb * 8 + b, col = ct * 16 + j;
  Wp[tid] = f2bf(W[k * 128 + col]);
}

// ---------------- MFMA GEMM: hp[n] = bf16( dinv[n] * (Xb[n] @ W) ) ----------------
// 64 rows/block, 4 waves x 16 rows; per wave 8 col-tiles x 4 k-steps of 16x16x32 MFMA.
__launch_bounds__(256)
__global__ void k_gemm(const u16* __restrict__ Xb, const u16* __restrict__ Wp,
                       const float* __restrict__ dinv, u16* __restrict__ hp) {
  __shared__ u16 wl[16384];        // packed W, 32 KB
  __shared__ u16 ctile[4][2048];   // per-wave epilogue staging, 16 KB
  int t = threadIdx.x;
  int w = t >> 6, l = t & 63;
  int row0 = blockIdx.x * 64;
  int rbase = row0 + w * 16;

  // cooperative load of packed W into LDS (8 x 16B per thread)
#pragma unroll
  for (int i = 0; i < 8; ++i) {
    int off = (i * 256 + t) * 8;
    *(uint4*)&wl[off] = *(const uint4*)&Wp[off];
  }
  __syncthreads();

  // A fragments from global: lane l -> row rbase+(l&15), k-chunk (l>>4)*8, 4 k-steps
  int arow = rbase + (l & 15);
  arow = arow < NN ? arow : NN - 1;
  const u16* abase = Xb + (size_t)arow * DIM + (l >> 4) * 8;
  bf16x8 a[4];
#pragma unroll
  for (int ks = 0; ks < 4; ++ks) a[ks] = *(const bf16x8*)(abase + ks * 32);

  f32x4 acc[8];
#pragma unroll
  for (int ct = 0; ct < 8; ++ct) {
    acc[ct] = (f32x4){0.f, 0.f, 0.f, 0.f};
#pragma unroll
    for (int ks = 0; ks < 4; ++ks) {
      bf16x8 bfr = *(const bf16x8*)&wl[ct * 2048 + ks * 512 + (l >> 4) * 128 + (l & 15) * 8];
      acc[ct] = __builtin_amdgcn_mfma_f32_16x16x32_bf16(a[ks], bfr, acc[ct], 0, 0, 0);
    }
  }

  // epilogue: dinv scale -> bf16 -> LDS tile -> coalesced row writes
  float dv[4];
#pragma unroll
  for (int v = 0; v < 4; ++v) {
    int rr = rbase + (l >> 4) * 4 + v;
    dv[v] = dinv[rr < NN ? rr : NN - 1];
  }
  u16* ct_lds = ctile[w];
#pragma unroll
  for (int ct = 0; ct < 8; ++ct) {
#pragma unroll
    for (int v = 0; v < 4; ++v) {
      int row = (l >> 4) * 4 + v;
      ct_lds[row * DIM + ct * 16 + (l & 15)] = f2bf(dv[v] * acc[ct][v]);
    }
  }
  __syncthreads();
#pragma unroll
  for (int rr = 0; rr < 4; ++rr) {
    int row = rr * 4 + (l >> 4);
    int grow = rbase + row;
    if (grow < NN)
      *(uint4*)&hp[(size_t)grow * DIM + (l & 15) * 8] =
          *(const uint4*)&ct_lds[row * DIM + (l & 15) * 8];
  }
}

// ---------------- aggregation on bf16 h': out = bf16( dn*(sum h'[u] + h'[n]) + b ) ----
// 256 threads = 8 groups of 32 lanes; group owns one node; lane owns 4 channels (8 B bf16).
__launch_bounds__(256)
__global__ void k_agg(const u16* __restrict__ hp, const int* __restrict__ csr_src,
                      const int* __restrict__ offs, const int* __restrict__ deg,
                      const float* __restrict__ dinv, const float* __restrict__ bias,
                      u16* __restrict__ outb, int relu) {
  int t = threadIdx.x;
  int g = t >> 5, l = t & 31;
  int n = blockIdx.x * 8 + g;          // NN/8 exact
  float dn = dinv[n];
  int s = offs[n], cnt = deg[n];
  const uint2* hp2 = (const uint2*)hp;   // 4 bf16 per uint2, 32 per row
  float a0 = 0.f, a1 = 0.f, a2 = 0.f, a3 = 0.f;
  int i = 0;
  for (; i + 4 <= cnt; i += 4) {
    int u0 = csr_src[s + i];
    int u1 = csr_src[s + i + 1];
    int u2 = csr_src[s + i + 2];
    int u3 = csr_src[s + i + 3];
    uint2 v0 = hp2[(size_t)u0 * 32 + l];
    uint2 v1 = hp2[(size_t)u1 * 32 + l];
    uint2 v2 = hp2[(size_t)u2 * 32 + l];
    uint2 v3 = hp2[(size_t)u3 * 32 + l];
    a0 += (bflo(v0.x) + bflo(v1.x)) + (bflo(v2.x) + bflo(v3.x));
    a1 += (bfhi(v0.x) + bfhi(v1.x)) + (bfhi(v2.x) + bfhi(v3.x));
    a2 += (bflo(v0.y) + bflo(v1.y)) + (bflo(v2.y) + bflo(v3.y));
    a3 += (bfhi(v0.y) + bfhi(v1.y)) + (bfhi(v2.y) + bfhi(v3.y));
  }
  for (; i < cnt; ++i) {
    int u = csr_src[s + i];
    uint2 v = hp2[(size_t)u * 32 + l];
    a0 += bflo(v.x); a1 += bfhi(v.x); a2 += bflo(v.y); a3 += bfhi(v.y);
  }
  uint2 sv = hp2[(size_t)n * 32 + l];
  float4 bb = ((const float4*)bias)[l];
  float r0 = dn * (a0 + bflo(sv.x)) + bb.x;
  float r1 = dn * (a1 + bfhi(sv.x)) + bb.y;
  float r2 = dn * (a2 + bflo(sv.y)) + bb.z;
  float r3 = dn * (a3 + bfhi(sv.y)) + bb.w;
  if (relu) {
    r0 = fmaxf(r0, 0.f); r1 = fmaxf(r1, 0.f);
    r2 = fmaxf(r2, 0.f); r3 = fmaxf(r3, 0.f);
  }
  ushort4 o; o.x = f2bf(r0); o.y = f2bf(r1); o.z = f2bf(r2); o.w = f2bf(r3);
  *(ushort4*)&outb[(size_t)n * DIM + l * 4] = o;
}

// ---------------- decode on bf16 z, CSR (dst-sorted) order ----------------
__global__ void k_decode_csr(const u16* __restrict__ z, const int* __restrict__ csr_src,
                             const int* __restrict__ csr_dst, const int* __restrict__ csr_eid,
                             float* __restrict__ out) {
  int g = blockIdx.x * blockDim.x + threadIdx.x;
  int l = g & 15;
  int p = g >> 4;
  if (p >= NE) return;
  int s = csr_src[p], d = csr_dst[p], e = csr_eid[p];
  const uint4* z4 = (const uint4*)z;     // 8 bf16 per uint4, 16 per row
  uint4 a = z4[(size_t)s * 16 + l];
  uint4 b = z4[(size_t)d * 16 + l];
  float acc = bflo(a.x) * bflo(b.x) + bfhi(a.x) * bfhi(b.x)
            + bflo(a.y) * bflo(b.y) + bfhi(a.y) * bfhi(b.y)
            + bflo(a.z) * bflo(b.z) + bfhi(a.z) * bfhi(b.z)
            + bflo(a.w) * bflo(b.w) + bfhi(a.w) * bfhi(b.w);
#pragma unroll
  for (int off = 8; off >= 1; off >>= 1) acc += __shfl_xor(acc, off);
  if (l == 0) out[e] = 1.0f / (1.0f + expf(-acc));
}

extern "C" void kernel_launch(void* const* d_in, const int* in_sizes, int n_in,
                              void* d_out, int out_size, void* d_ws, size_t ws_size,
                              hipStream_t stream) {
  const float* x  = (const float*)d_in[0];
  const float* W1 = (const float*)d_in[1];
  const float* b1 = (const float*)d_in[2];
  const float* W2 = (const float*)d_in[3];
  const float* b2 = (const float*)d_in[4];
  const float* W3 = (const float*)d_in[5];
  const float* b3 = (const float*)d_in[6];
  const int*   ei = (const int*)d_in[7];
  const int* src = ei;
  const int* dst = ei + NE;
  float* out = (float*)d_out;

  char* w = (char*)d_ws;
  size_t p = 0;
  auto alloc = [&](size_t bytes) -> void* {
    void* r = w + p;
    p += (bytes + 255) & ~(size_t)255;
    return r;
  };
  int*   deg     = (int*)alloc((size_t)NN * 4);
  int*   cur     = (int*)alloc((size_t)NN * 4);
  int*   offs    = (int*)alloc((size_t)NN * 4);
  float* dinv    = (float*)alloc((size_t)NN * 4);
  int*   bsum    = (int*)alloc(1024);
  int*   csr_src = (int*)alloc((size_t)NE * 4);
  int*   csr_dst = (int*)alloc((size_t)NE * 4);
  int*   csr_eid = (int*)alloc((size_t)NE * 4);
  u16*   Xb      = (u16*)alloc((size_t)NN * DIM * 2);   // bf16 input features
  u16*   hp      = (u16*)alloc((size_t)NN * DIM * 2);   // bf16 GEMM out (premult by dinv)
  u16*   hb      = (u16*)alloc((size_t)NN * DIM * 2);   // bf16 agg out (next GEMM input / z)
  u16*   Wp1     = (u16*)alloc(16384 * 2);
  u16*   Wp2     = (u16*)alloc(16384 * 2);
  u16*   Wp3     = (u16*)alloc(16384 * 2);
  (void)in_sizes; (void)n_in; (void)out_size; (void)ws_size;

  hipMemsetAsync(deg, 0, (size_t)NN * 4, stream);
  hipMemsetAsync(cur, 0, (size_t)NN * 4, stream);

  k_deg<<<(NE + 255) / 256, 256, 0, stream>>>(dst, deg);
  k_dinv<<<(NN + 255) / 256, 256, 0, stream>>>(deg, dinv);
  int nb = (NN + SCHUNK - 1) / SCHUNK;  // 98
  k_scan1<<<nb, 256, 0, stream>>>(deg, bsum);
  k_scan2<<<1, 64, 0, stream>>>(bsum, nb);
  k_scan3<<<nb, 256, 0, stream>>>(deg, bsum, offs);
  k_fill<<<(NE + 255) / 256, 256, 0, stream>>>(src, dst, offs, cur, csr_src, csr_dst, csr_eid);

  k_tobf<<<(NN * DIM / 4 + 255) / 256, 256, 0, stream>>>(x, Xb, NN * DIM / 4);
  k_pack<<<64, 256, 0, stream>>>(W1, Wp1);
  k_pack<<<64, 256, 0, stream>>>(W2, Wp2);
  k_pack<<<64, 256, 0, stream>>>(W3, Wp3);

  int gb = (NN + 63) / 64;  // 1563
  k_gemm<<<gb, 256, 0, stream>>>(Xb, Wp1, dinv, hp);
  k_agg <<<NN / 8, 256, 0, stream>>>(hp, csr_src, offs, deg, dinv, b1, hb, 1);
  k_gemm<<<gb, 256, 0, stream>>>(hb, Wp2, dinv, hp);
  k_agg <<<NN / 8, 256, 0, stream>>>(hp, csr_src, offs, deg, dinv, b2, hb, 1);
  k_gemm<<<gb, 256, 0, stream>>>(hb, Wp3, dinv, hp);
  k_agg <<<NN / 8, 256, 0, stream>>>(hp, csr_src, offs, deg, dinv, b3, hb, 0);

  k_decode_csr<<<(NE * 16 + 255) / 256, 256, 0, stream>>>(hb, csr_src, csr_dst, csr_eid, out);
}